// Round 1
// baseline (805.336 us; speedup 1.0000x reference)
//
#include <hip/hip_runtime.h>
#include <math.h>

// Packed variable-length softmax over rows.
// Static shape (from reference): SEQ_LEN=(1024,2048,512,1536), HEAD_NUM=16.
// Row-space layout (row = one softmax row of length s):
//   seg0: rows [0,     16384)  s=1024  base elem      0
//   seg1: rows [16384, 49152)  s=2048  base elem 16777216
//   seg2: rows [49152, 57344)  s=512   base elem 83886080
//   seg3: rows [57344, 81920)  s=1536  base elem 88080384
// Total rows 81920, total elems 125829120 (0.503 GB in + 0.503 GB out).
//
// Design: ONE WAVE PER ROW, row length as a template parameter.
//  - per-lane row cache is a compile-time-sized array (2/4/6/8 float4),
//    statically indexed and fully unrolled -> stays in VGPRs (never scratch)
//  - reductions are pure wave-level __shfl_xor (no LDS, no __syncthreads)
//  - 4 waves per 256-thread block work on 4 independent rows; the segment
//    branch is wave-uniform (a wave never straddles a row)
//  - non-temporal stores for the write-once output stream

typedef float f32x4 __attribute__((ext_vector_type(4)));

#define NROWS 81920
#define NBLOCKS (NROWS / 4)

template <int S>
__device__ __forceinline__ void softmax_row_wave(
    const float* __restrict__ rowf, float* __restrict__ outf, int lane) {
    constexpr int PER = S / 4 / 64;  // float4 per lane: 512->2, 1024->4, 1536->6, 2048->8
    const f32x4* __restrict__ rowp = (const f32x4*)rowf;
    f32x4* __restrict__ outp = (f32x4*)outf;

    // ---- load row into registers (static count), local max ----
    f32x4 v[PER];
    float lmax = -INFINITY;
#pragma unroll
    for (int k = 0; k < PER; ++k) {
        f32x4 t = rowp[lane + 64 * k];
        v[k] = t;
        lmax = fmaxf(lmax, fmaxf(fmaxf(t.x, t.y), fmaxf(t.z, t.w)));
    }

    // ---- wave reduce max (64 lanes, 6 steps) ----
#pragma unroll
    for (int off = 32; off; off >>= 1)
        lmax = fmaxf(lmax, __shfl_xor(lmax, off, 64));

    // ---- exp in-register, local sum ----
    float lsum = 0.0f;
#pragma unroll
    for (int k = 0; k < PER; ++k) {
        f32x4 t = v[k];
        t.x = __expf(t.x - lmax);
        t.y = __expf(t.y - lmax);
        t.z = __expf(t.z - lmax);
        t.w = __expf(t.w - lmax);
        v[k] = t;
        lsum += (t.x + t.y) + (t.z + t.w);
    }

    // ---- wave reduce sum ----
#pragma unroll
    for (int off = 32; off; off >>= 1)
        lsum += __shfl_xor(lsum, off, 64);
    const float inv = 1.0f / lsum;

    // ---- scale + non-temporal store (coalesced: 64 lanes x 16B = 1 KiB/instr) ----
#pragma unroll
    for (int k = 0; k < PER; ++k) {
        f32x4 t = v[k];
        t.x *= inv; t.y *= inv; t.z *= inv; t.w *= inv;
        __builtin_nontemporal_store(t, &outp[lane + 64 * k]);
    }
}

__global__ __launch_bounds__(256) void fast_softmax_kernel(
    const float* __restrict__ x, float* __restrict__ out) {
    const int wid  = threadIdx.x >> 6;   // wave id within block: 0..3
    const int lane = threadIdx.x & 63;
    const int row  = (blockIdx.x << 2) + wid;  // one wave per row

    if (row < 16384) {
        const int e0 = row << 10;                               // *1024
        softmax_row_wave<1024>(x + e0, out + e0, lane);
    } else if (row < 49152) {
        const int e0 = 16777216 + ((row - 16384) << 11);        // *2048
        softmax_row_wave<2048>(x + e0, out + e0, lane);
    } else if (row < 57344) {
        const int e0 = 83886080 + ((row - 49152) << 9);         // *512
        softmax_row_wave<512>(x + e0, out + e0, lane);
    } else {
        const int e0 = 88080384 + (row - 57344) * 1536;
        softmax_row_wave<1536>(x + e0, out + e0, lane);
    }
}

extern "C" void kernel_launch(void* const* d_in, const int* in_sizes, int n_in,
                              void* d_out, int out_size, void* d_ws, size_t ws_size,
                              hipStream_t stream) {
    const float* x = (const float*)d_in[0];
    float* out = (float*)d_out;
    fast_softmax_kernel<<<NBLOCKS, 256, 0, stream>>>(x, out);
}

// Round 2
// 789.748 us; speedup vs baseline: 1.0197x; 1.0197x over previous
//
#include <hip/hip_runtime.h>
#include <math.h>

// Packed variable-length softmax over rows.
// Static shape (from reference): SEQ_LEN=(1024,2048,512,1536), HEAD_NUM=16.
// Row-space layout (row = one softmax row of length s):
//   seg0: rows [0,     16384)  s=1024  base elem      0
//   seg1: rows [16384, 49152)  s=2048  base elem 16777216
//   seg2: rows [49152, 57344)  s=512   base elem 83886080
//   seg3: rows [57344, 81920)  s=1536  base elem 88080384
// Total rows 81920, total elems 125829120 (0.503 GB in + 0.503 GB out).
//
// Design: ONE WAVE PER ROW, row length as a template parameter.
//  - per-lane row cache is a compile-time-sized array (2/4/6/8 float4),
//    statically indexed and fully unrolled -> stays in VGPRs (never scratch)
//  - reductions are pure wave-level __shfl_xor (no LDS, no __syncthreads)
//  - 4 waves per 256-thread block work on 4 independent rows; the segment
//    branch is wave-uniform (a wave never straddles a row)
//  - PLAIN stores this round (round-1 used non-temporal stores and regressed
//    772.5 -> 805.3 us; NT bypasses L2 write aggregation -- this is the A/B)

typedef float f32x4 __attribute__((ext_vector_type(4)));

#define NROWS 81920
#define NBLOCKS (NROWS / 4)

template <int S>
__device__ __forceinline__ void softmax_row_wave(
    const float* __restrict__ rowf, float* __restrict__ outf, int lane) {
    constexpr int PER = S / 4 / 64;  // float4 per lane: 512->2, 1024->4, 1536->6, 2048->8
    const f32x4* __restrict__ rowp = (const f32x4*)rowf;
    f32x4* __restrict__ outp = (f32x4*)outf;

    // ---- load row into registers (static count), local max ----
    f32x4 v[PER];
    float lmax = -INFINITY;
#pragma unroll
    for (int k = 0; k < PER; ++k) {
        f32x4 t = rowp[lane + 64 * k];
        v[k] = t;
        lmax = fmaxf(lmax, fmaxf(fmaxf(t.x, t.y), fmaxf(t.z, t.w)));
    }

    // ---- wave reduce max (64 lanes, 6 steps) ----
#pragma unroll
    for (int off = 32; off; off >>= 1)
        lmax = fmaxf(lmax, __shfl_xor(lmax, off, 64));

    // ---- exp in-register, local sum ----
    float lsum = 0.0f;
#pragma unroll
    for (int k = 0; k < PER; ++k) {
        f32x4 t = v[k];
        t.x = __expf(t.x - lmax);
        t.y = __expf(t.y - lmax);
        t.z = __expf(t.z - lmax);
        t.w = __expf(t.w - lmax);
        v[k] = t;
        lsum += (t.x + t.y) + (t.z + t.w);
    }

    // ---- wave reduce sum ----
#pragma unroll
    for (int off = 32; off; off >>= 1)
        lsum += __shfl_xor(lsum, off, 64);
    const float inv = 1.0f / lsum;

    // ---- scale + store (coalesced: 64 lanes x 16B = 1 KiB/instr) ----
#pragma unroll
    for (int k = 0; k < PER; ++k) {
        f32x4 t = v[k];
        t.x *= inv; t.y *= inv; t.z *= inv; t.w *= inv;
        outp[lane + 64 * k] = t;
    }
}

__global__ __launch_bounds__(256) void fast_softmax_kernel(
    const float* __restrict__ x, float* __restrict__ out) {
    const int wid  = threadIdx.x >> 6;   // wave id within block: 0..3
    const int lane = threadIdx.x & 63;
    const int row  = (blockIdx.x << 2) + wid;  // one wave per row

    if (row < 16384) {
        const int e0 = row << 10;                               // *1024
        softmax_row_wave<1024>(x + e0, out + e0, lane);
    } else if (row < 49152) {
        const int e0 = 16777216 + ((row - 16384) << 11);        // *2048
        softmax_row_wave<2048>(x + e0, out + e0, lane);
    } else if (row < 57344) {
        const int e0 = 83886080 + ((row - 49152) << 9);         // *512
        softmax_row_wave<512>(x + e0, out + e0, lane);
    } else {
        const int e0 = 88080384 + (row - 57344) * 1536;
        softmax_row_wave<1536>(x + e0, out + e0, lane);
    }
}

extern "C" void kernel_launch(void* const* d_in, const int* in_sizes, int n_in,
                              void* d_out, int out_size, void* d_ws, size_t ws_size,
                              hipStream_t stream) {
    const float* x = (const float*)d_in[0];
    float* out = (float*)d_out;
    fast_softmax_kernel<<<NBLOCKS, 256, 0, stream>>>(x, out);
}